// Round 8
// baseline (141.996 us; speedup 1.0000x reference)
//
#include <hip/hip_runtime.h>
#include <math.h>

// KTVLoss: inputs out_l, out_r, input_i : (8,3,512,512) fp32. Output: 1 fp32 scalar.
//
// Sx = 10x10 box sum of |dI/dh| (502x503), Sy = box sum of |dI/dw| (503x502).
// Reference pairs them by FLAT index: Sx(i,j) with Sy(i,i+j) if i+j<502 else
// Sy(i+1,i+j-502). ratio = (SxL+SyL+SxR+SyR)/(SxI+SyI+1e-4), mean over 24*502*503.
// grad part (fp32): mean|GxL+GxR-GxI| + mean|GyL+GyR-GyI| over 24*511*512 each.
// norm part carries a 1e-4 weight -> packed f16 (abs error ~1e-5; passed 3 rounds).
//
// R8 restructure: BARRIER-FREE two-pass bands (R7 was barrier-bound: 35
// block-wide barriers, VALUBusy 34%, occ 18%).
//  - Each wave owns a 64-col strip and loads its own 10-col halo (v1, lanes
//    0..9) -> horizontal 10-window fully wave-local: two DPP prefix scans
//    (main A + halo A2), h = (lane<=54 ? A[l+9] : T+A2[l-55]) - A[l-1].
//  - Pass A: stream 30 rows, vertical Sy ring in regs, write completed Sy
//    rows to LDS (21 x 502 f16x2 = 42 KB).  ONE barrier.
//  - Pass B: re-stream rows (L3-hot), Sx ring, read paired Sy from LDS.
// No cross-wave data inside a pass => no per-step barrier, waves free-run.
// VGPR cap law (R4-R7): cap = 256/min_waves; (512,2) -> 128, no spill.

namespace {

constexpr int H = 512, W = 512;
constexpr int CX = 503;          // Sx cols (and Sy row count)
constexpr int CY = 502;          // Sy cols (and Sx row count)
constexpr int RB = 20;           // Sx rows per band
constexpr int NBANDS = 26;       // ceil(502/20)
constexpr int NIMG = 24;
constexpr int NBLOCKS = NIMG * NBANDS;   // 624
constexpr int NSTEP = RB + 10;           // 30 (3 chunks of 10)

typedef __fp16 h2 __attribute__((ext_vector_type(2)));

__device__ __forceinline__ int h2i(h2 v) { int r; __builtin_memcpy(&r, &v, 4); return r; }
__device__ __forceinline__ h2 i2h(int v) { h2 r; __builtin_memcpy(&r, &v, 4); return r; }

template <int C, int RM>
__device__ __forceinline__ int dppmov(int v) {
  return __builtin_amdgcn_update_dpp(0, v, C, RM, 0xf, true);
}
// full 64-lane inclusive prefix sum of a f16x2 pack (pure VALU)
__device__ __forceinline__ h2 scan64(h2 v) {
  v += i2h(dppmov<0x111, 0xf>(h2i(v)));  // row_shr:1
  v += i2h(dppmov<0x112, 0xf>(h2i(v)));  // row_shr:2
  v += i2h(dppmov<0x114, 0xf>(h2i(v)));  // row_shr:4
  v += i2h(dppmov<0x118, 0xf>(h2i(v)));  // row_shr:8
  v += i2h(dppmov<0x142, 0xa>(h2i(v)));  // row_bcast15 -> rows 1,3
  v += i2h(dppmov<0x143, 0xc>(h2i(v)));  // row_bcast31 -> rows 2,3
  return v;
}
__device__ __forceinline__ float wshl1(float v) {  // lane i <- lane i+1
  return __int_as_float(__builtin_amdgcn_update_dpp(0, __float_as_int(v), 0x130, 0xf, 0xf, true));
}

}  // namespace

// horizontal 10-window from packed strip value E (own cols) + halo E2 (lanes 0..8)
#define HWIN(E, E2, OUT)                                                        \
  const h2 A_ = scan64(E), A2_ = scan64(E2);                                    \
  const h2 Aex_ = i2h(dppmov<0x138, 0xf>(h2i(A_)));  /* A[lane-1], 0 @ lane0 */ \
  const h2 T_ = i2h(__builtin_amdgcn_readlane(h2i(A_), 63));                    \
  const h2 t9_ = i2h(__shfl(h2i(A_), lane + 9));                                \
  const h2 t2_ = i2h(__shfl(h2i(A2_), lane - 55));                              \
  const h2 OUT = (lane <= 54 ? t9_ : T_ + t2_) - Aex_;

// ---- pass A step: gy row r, Sy vertical ring, write Sy rows to LDS ----
#define STEPA(SS, U)                                                            \
  {                                                                             \
    const int s_ = (SS);                                                        \
    const int r = i0 + s_;                                                      \
    const float xl = nAL, xr = nAR, xi = nAI;                                   \
    const float bl = nBL, br = nBR, bi = nBI;                                   \
    if (r + 1 < H) {                                                            \
      nAL = pL[offN]; nAR = pR[offN]; nAI = pI[offN];                           \
      if (vok) { nBL = pL[offN + 64]; nBR = pR[offN + 64]; nBI = pI[offN + 64]; } \
      offN += W;                                                                \
    }                                                                           \
    float nxl = wshl1(xl), nxr = wshl1(xr), nxi = wshl1(xi);                    \
    const float x64l = __shfl(bl, 0), x64r = __shfl(br, 0), x64i = __shfl(bi, 0); \
    if (lane == 63) { nxl = x64l; nxr = x64r; nxi = x64i; }                     \
    const float gyl = nxl - xl, gyr = nxr - xr, gyi = nxi - xi;                 \
    if (r < gyEnd && col < W - 1) accGY += fabsf(gyl + gyr - gyi);              \
    const bool ev = (col < W - 1) && (r < H);                                   \
    const float yn = ev ? (fabsf(gyl) + fabsf(gyr)) : 0.f;                      \
    const float yd = ev ? fabsf(gyi) : 0.f;                                     \
    const float b1l = wshl1(bl), b1r = wshl1(br), b1i = wshl1(bi);              \
    const float g2l = b1l - bl, g2r = b1r - br, g2i = b1i - bi;                 \
    const bool e2v = (lane <= 8) && vok && (r < H);                             \
    const float y2n = e2v ? (fabsf(g2l) + fabsf(g2r)) : 0.f;                    \
    const float y2d = e2v ? fabsf(g2i) : 0.f;                                   \
    const h2 E = __builtin_amdgcn_cvt_pkrtz(yn, yd);                            \
    const h2 E2 = __builtin_amdgcn_cvt_pkrtz(y2n, y2d);                         \
    HWIN(E, E2, hh)                                                             \
    runY += hh - histY[U]; histY[U] = hh;                                       \
    if (s_ >= 9) {                                                              \
      const int iY = r - 9;                                                     \
      if (iY <= syEnd && col < CY) syLDS[s_ - 9][col] = h2i(runY);              \
    }                                                                           \
  }

// ---- pass B step: gx row r (= x[r+1]-x[r]), Sx ring, paired ratio ----
#define STEPB(SS, U)                                                            \
  {                                                                             \
    const int s_ = (SS);                                                        \
    const int r = i0 + s_;                                                      \
    const float gxl = nAL - cAL, gxr = nAR - cAR, gxi = nAI - cAI;              \
    const float g2l = nBL - cBL, g2r = nBR - cBR, g2i = nBI - cBI;              \
    cAL = nAL; cAR = nAR; cAI = nAI;                                            \
    cBL = nBL; cBR = nBR; cBI = nBI;                                            \
    if (r + 2 < H) {                                                            \
      nAL = pL[offN]; nAR = pR[offN]; nAI = pI[offN];                           \
      if (vok) { nBL = pL[offN + 64]; nBR = pR[offN + 64]; nBI = pI[offN + 64]; } \
      offN += W;                                                                \
    }                                                                           \
    if (r < gxEnd) accGX += fabsf(gxl + gxr - gxi);                             \
    const bool ev = (r < H - 1);                                                \
    const float xn = ev ? (fabsf(gxl) + fabsf(gxr)) : 0.f;                      \
    const float xd = ev ? fabsf(gxi) : 0.f;                                     \
    const bool e2v = (lane <= 8) && vok && ev;                                  \
    const float x2n = e2v ? (fabsf(g2l) + fabsf(g2r)) : 0.f;                    \
    const float x2d = e2v ? fabsf(g2i) : 0.f;                                   \
    const h2 E = __builtin_amdgcn_cvt_pkrtz(xn, xd);                            \
    const h2 E2 = __builtin_amdgcn_cvt_pkrtz(x2n, x2d);                         \
    HWIN(E, E2, hh)                                                             \
    runX += hh - histX[U]; histX[U] = hh;                                       \
    if (s_ >= 9) {                                                              \
      const int iX = r - 9;                                                     \
      if (iX < sxEnd && col < CX) {                                             \
        int jy = iX + col, rw = s_ - 9;                                         \
        if (jy >= CY) { jy -= CY; ++rw; }                                       \
        const h2 sy = i2h(syLDS[rw][jy]);                                       \
        const float num = (float)runX.x + (float)sy.x;                          \
        const float den = (float)runX.y + (float)sy.y + 1e-4f;                  \
        accN += num * __builtin_amdgcn_rcpf(den);                               \
      }                                                                         \
    }                                                                           \
  }

__global__ __launch_bounds__(512, 2) void ktv_main(const float* __restrict__ L,
                                                   const float* __restrict__ R,
                                                   const float* __restrict__ I,
                                                   double* __restrict__ partial) {
  const int blk = blockIdx.x;
  const int img = blk / NBANDS;
  const int band = blk % NBANDS;
  const int i0 = band * RB;
  const int j = threadIdx.x;
  const int lane = j & 63;
  const int wv = j >> 6;
  const int col = j;                       // global column = c + lane, c = 64*wv
  const bool vok = (lane <= 9) && (wv < 7);  // halo loader lanes (cols c+64..c+73)

  const bool lastb = (band == NBANDS - 1);
  const int gyEnd = lastb ? H : (i0 + RB);          // Gy rows owned [i0, gyEnd)
  const int gxEnd = lastb ? (H - 1) : (i0 + RB);    // Gx rows owned [i0, gxEnd)
  const int sxEnd = lastb ? CY : (i0 + RB);         // Sx rows owned [i0, sxEnd)
  const int syEnd = sxEnd;                          // Sy rows needed [i0, syEnd]

  const size_t base = (size_t)img * (H * W);
  const float* pL = L + base;
  const float* pR = R + base;
  const float* pI = I + base;

  __shared__ int syLDS[RB + 1][CY];   // Sy rows i0..i0+RB (f16x2 n,d) = 42.2 KB
  __shared__ float redN[8], redGX[8], redGY[8];

  float accN = 0.f, accGX = 0.f, accGY = 0.f;

  // ================= pass A: Sy =================
  {
    h2 histY[10];
#pragma unroll
    for (int t = 0; t < 10; ++t) histY[t] = (h2)(__fp16)0;
    h2 runY = (h2)(__fp16)0;
    int offN = i0 * W + col;
    float nAL = pL[offN], nAR = pR[offN], nAI = pI[offN];
    float nBL = 0.f, nBR = 0.f, nBI = 0.f;
    if (vok) { nBL = pL[offN + 64]; nBR = pR[offN + 64]; nBI = pI[offN + 64]; }
    offN += W;

#pragma unroll 1
    for (int t = 0; t < 3; ++t) {
      const int sb = t * 10;
      STEPA(sb + 0, 0) STEPA(sb + 1, 1) STEPA(sb + 2, 2) STEPA(sb + 3, 3)
      STEPA(sb + 4, 4) STEPA(sb + 5, 5) STEPA(sb + 6, 6) STEPA(sb + 7, 7)
      STEPA(sb + 8, 8) STEPA(sb + 9, 9)
    }
  }

  __syncthreads();  // the ONLY inter-pass barrier

  // ================= pass B: Sx + ratio =================
  {
    h2 histX[10];
#pragma unroll
    for (int t = 0; t < 10; ++t) histX[t] = (h2)(__fp16)0;
    h2 runX = (h2)(__fp16)0;
    int offN = i0 * W + col;
    float cAL = pL[offN], cAR = pR[offN], cAI = pI[offN];
    float cBL = 0.f, cBR = 0.f, cBI = 0.f;
    if (vok) { cBL = pL[offN + 64]; cBR = pR[offN + 64]; cBI = pI[offN + 64]; }
    float nAL = pL[offN + W], nAR = pR[offN + W], nAI = pI[offN + W];
    float nBL = 0.f, nBR = 0.f, nBI = 0.f;
    if (vok) { nBL = pL[offN + W + 64]; nBR = pR[offN + W + 64]; nBI = pI[offN + W + 64]; }
    offN += 2 * W;

#pragma unroll 1
    for (int t = 0; t < 3; ++t) {
      const int sb = t * 10;
      STEPB(sb + 0, 0) STEPB(sb + 1, 1) STEPB(sb + 2, 2) STEPB(sb + 3, 3)
      STEPB(sb + 4, 4) STEPB(sb + 5, 5) STEPB(sb + 6, 6) STEPB(sb + 7, 7)
      STEPB(sb + 8, 8) STEPB(sb + 9, 9)
    }
  }

  // ---- block reduction ----
#pragma unroll
  for (int o2 = 32; o2 > 0; o2 >>= 1) {
    accN  += __shfl_down(accN, o2);
    accGX += __shfl_down(accGX, o2);
    accGY += __shfl_down(accGY, o2);
  }
  if (lane == 0) { redN[wv] = accN; redGX[wv] = accGX; redGY[wv] = accGY; }
  __syncthreads();
  if (j == 0) {
    float n = 0.f, gx = 0.f, gy = 0.f;
#pragma unroll
    for (int w2 = 0; w2 < 8; ++w2) { n += redN[w2]; gx += redGX[w2]; gy += redGY[w2]; }
    double* p = partial + (size_t)blk * 3;
    p[0] = (double)n; p[1] = (double)gx; p[2] = (double)gy;
  }
}

__global__ __launch_bounds__(64) void ktv_reduce(const double* __restrict__ partial,
                                                 float* __restrict__ out) {
  double n = 0.0, gx = 0.0, gy = 0.0;
  for (int i = threadIdx.x; i < NBLOCKS; i += 64) {
    const double* p = partial + (size_t)i * 3;
    n += p[0]; gx += p[1]; gy += p[2];
  }
#pragma unroll
  for (int o2 = 32; o2 > 0; o2 >>= 1) {
    n  += __shfl_down(n, o2);
    gx += __shfl_down(gx, o2);
    gy += __shfl_down(gy, o2);
  }
  if (threadIdx.x == 0) {
    const double norm_loss = n / 6060144.0;          // 24*502*503
    const double grad_loss = (gx + gy) / 6279168.0;  // 24*511*512
    out[0] = (float)(1e-4 * norm_loss + grad_loss);
  }
}

extern "C" void kernel_launch(void* const* d_in, const int* in_sizes, int n_in,
                              void* d_out, int out_size, void* d_ws, size_t ws_size,
                              hipStream_t stream) {
  (void)in_sizes; (void)n_in; (void)out_size; (void)ws_size;
  const float* L = (const float*)d_in[0];
  const float* R = (const float*)d_in[1];
  const float* I = (const float*)d_in[2];
  double* partial = (double*)d_ws;   // NBLOCKS*3 doubles = 14976 B
  float* out = (float*)d_out;

  hipLaunchKernelGGL(ktv_main, dim3(NBLOCKS), dim3(512), 0, stream, L, R, I, partial);
  hipLaunchKernelGGL(ktv_reduce, dim3(1), dim3(64), 0, stream, partial, out);
}